// Round 8
// baseline (135.765 us; speedup 1.0000x reference)
//
#include <hip/hip_runtime.h>
#include <stdint.h>

namespace {

constexpr int kB       = 8;
constexpr int kT       = 4096;
constexpr int kC4      = 256;            // 1024 f32 channels as float4
constexpr int kSub     = 16;             // timesteps per tile
constexpr int kSegPerB = kT / kSub;      // 256 tiles per batch chain
constexpr int kTiles   = kB * kSegPerB;  // 2048 blocks

constexpr size_t kStOff   = 256;         // ticket counter at d_ws[0]
constexpr size_t kStWords = (size_t)kTiles * 4 * kC4;   // 2M u64 = 16 MiB

typedef float f4 __attribute__((ext_vector_type(4)));

__device__ __forceinline__ uint64_t ld_st(const uint64_t* p) {
    return __hip_atomic_load(p, __ATOMIC_RELAXED, __HIP_MEMORY_SCOPE_AGENT);
}
__device__ __forceinline__ void st_st(uint64_t* p, uint64_t w) {
    __hip_atomic_store(p, w, __ATOMIC_RELAXED, __HIP_MEMORY_SCOPE_AGENT);
}
// state word per (b, seg, component j, c4): (float_bits<<32) | tag
// tag: 0 = invalid, 1 = tile aggregate, 2 = inclusive chain prefix
__device__ __forceinline__ size_t sidx(int b, int s, int j, int c4) {
    return ((size_t)(((((b << 8) | s) << 2) | j)) << 8) | (unsigned)c4;
}

__global__ __launch_bounds__(256, 4) void lb_scan(const float4* __restrict__ x,
                                                  float4* __restrict__ out,
                                                  uint32_t* __restrict__ ticket,
                                                  uint64_t* __restrict__ st) {
    __shared__ uint32_t s_tile;
    if (threadIdx.x == 0) s_tile = atomicAdd(ticket, 1u);
    __syncthreads();
    const uint32_t tile = s_tile;          // ticket order => preds already started
    const int b   = (int)(tile & 7u);      // interleave the 8 batch chains
    const int seg = (int)(tile >> 3);
    const int c4  = (int)threadIdx.x;

    // Phase 1: load my 16-timestep column (wave = 64 consecutive float4 = 1 KB/instr).
    const size_t base = ((size_t)(b * kT + seg * kSub)) * kC4 + c4;
    const float4* p = x + base;
    float4 v[kSub];
#pragma unroll
    for (int i = 0; i < kSub; ++i) v[i] = p[(size_t)i * kC4];
    float ax = 0.f, ay = 0.f, az = 0.f, aw = 0.f;
#pragma unroll
    for (int i = 0; i < kSub; ++i) {
        ax += v[i].x; ay += v[i].y; az += v[i].z; aw += v[i].w;
    }

    // Publish tile aggregate (seg 0 publishes its inclusive prefix directly).
    {
        const uint32_t tag = (seg == 0) ? 2u : 1u;
        const float a[4] = { ax, ay, az, aw };
#pragma unroll
        for (int j = 0; j < 4; ++j)
            st_st(st + sidx(b, seg, j, c4),
                  ((uint64_t)__float_as_uint(a[j]) << 32) | tag);
    }

    // Phase 2: backward windowed lookback with inclusive early-exit (CUB-style).
    float rx = 0.f, ry = 0.f, rz = 0.f, rw = 0.f;
    if (seg > 0) {
        bool done[4] = { false, false, false, false };
        float run[4] = { 0.f, 0.f, 0.f, 0.f };
        int s = seg - 1;
        while (!(done[0] && done[1] && done[2] && done[3])) {
            uint64_t w[4][4];
            bool ok = true;
#pragma unroll
            for (int k = 0; k < 4; ++k) {
                const int  sk = s - k;
                const bool in = sk >= 0;
#pragma unroll
                for (int j = 0; j < 4; ++j)
                    // pad below chain start with (value=0, tag=2): prefix(-1) == 0
                    w[k][j] = in ? ld_st(st + sidx(b, sk, j, c4)) : (uint64_t)2u;
            }
#pragma unroll
            for (int k = 0; k < 4; ++k)
#pragma unroll
                for (int j = 0; j < 4; ++j) ok &= ((uint32_t)w[k][j] != 0u);
            if (!ok) { __builtin_amdgcn_s_sleep(4); continue; }
#pragma unroll
            for (int k = 0; k < 4; ++k) {
#pragma unroll
                for (int j = 0; j < 4; ++j) {
                    if (!done[j]) {
                        run[j] += __uint_as_float((uint32_t)(w[k][j] >> 32));
                        done[j] = ((uint32_t)w[k][j] == 2u);  // hit an inclusive entry
                    }
                }
            }
            s -= 4;
        }
        rx = run[0]; ry = run[1]; rz = run[2]; rw = run[3];
        // Publish my inclusive prefix so successors early-exit at depth ~1.
        const float pr[4] = { rx + ax, ry + ay, rz + az, rw + aw };
#pragma unroll
        for (int j = 0; j < 4; ++j)
            st_st(st + sidx(b, seg, j, c4),
                  ((uint64_t)__float_as_uint(pr[j]) << 32) | 2u);
    }

    // Phase 3: running prefix + scale, nontemporal store stream.
    f4* o = (f4*)(out + base);
    const int t0 = seg * kSub;
    float ox = rx, oy = ry, oz = rz, ow = rw;
#pragma unroll
    for (int i = 0; i < kSub; ++i) {
        ox += v[i].x; oy += v[i].y; oz += v[i].z; ow += v[i].w;
        const float inv = __builtin_amdgcn_rcpf((float)(t0 + i + 1));
        f4 r;
        r.x = ox * inv; r.y = oy * inv; r.z = oz * inv; r.w = ow * inv;
        __builtin_nontemporal_store(r, o + (size_t)i * kC4);
    }
}

}  // namespace

extern "C" void kernel_launch(void* const* d_in, const int* in_sizes, int n_in,
                              void* d_out, int out_size, void* d_ws, size_t ws_size,
                              hipStream_t stream) {
    const float4* x = (const float4*)d_in[0];
    float4* out     = (float4*)d_out;
    uint32_t* ctr   = (uint32_t*)d_ws;
    uint64_t* st    = (uint64_t*)((char*)d_ws + kStOff);
    // Clear ticket + state tags every launch (graph-capturable, ~17 MiB ≈ 2.5 µs).
    (void)hipMemsetAsync(d_ws, 0, kStOff + kStWords * sizeof(uint64_t), stream);
    lb_scan<<<kTiles, 256, 0, stream>>>(x, out, ctr, st);
}